// Round 6
// baseline (175.580 us; speedup 1.0000x reference)
//
#include <hip/hip_runtime.h>
#include <hip/hip_bf16.h>
#include <hip/hip_cooperative_groups.h>

namespace cg = cooperative_groups;

// Problem constants
#define B_    64
#define C_    1280
#define HW_   49
#define A_    40
#define BN    128          // d-tile per block (R1 champion config)
#define BK    32           // k-step (R1 champion config)
#define NK    (C_/BK)      // 40
#define NTILE (C_/BN)      // 10
#define WLDS_STRIDE 40     // R1's LDS row stride (32 + 8 pad)
#define POOL_RPB 256       // pooled rows per block in phase A
#define NPOOLB ((B_*C_)/POOL_RPB)   // 320 blocks do pooling
#define NBLOCKS (NTILE*A_)          // 400

typedef short bf16x8 __attribute__((ext_vector_type(8)));
typedef short bf16x4 __attribute__((ext_vector_type(4)));
typedef float f32x4  __attribute__((ext_vector_type(4)));

__device__ __forceinline__ float hswish(float x) {
    float t = fminf(fmaxf(x + 3.0f, 0.0f), 6.0f);
    return x * t * (1.0f / 6.0f);
}

__device__ __forceinline__ short f2bf(float f) {
    __hip_bfloat16 h = __float2bfloat16(f);
    return __builtin_bit_cast(short, h);
}

union LdsU {
    float pool[POOL_RPB * HW_];                            // 50176 B
    struct { short w[BN * WLDS_STRIDE]; short pl[B_ * BK]; } head;  // 14336 B
};

__global__ __launch_bounds__(256) void fused_kernel(
    const float* __restrict__ x,     // [64][1280][49]
    const float* __restrict__ W1,    // [40][1280][1280]  ([a][k][d])
    const float* __restrict__ b1,    // [40][1280]
    const float* __restrict__ W2,    // [40][1280]
    const float* __restrict__ b2,    // [40]
    short* __restrict__ p,           // ws: [64][1280] bf16
    float* __restrict__ part,        // ws: [NTILE][64][40]
    float* __restrict__ out)         // [64][40]
{
    __shared__ LdsU u;

    const int tid  = threadIdx.x;
    const int bid  = blockIdx.x;
    const int lane = tid & 63;
    const int wid  = tid >> 6;

    // head mapping identical to R1's dim3(NTILE, A_) dispatch order
    const int ntile = bid % NTILE;
    const int a     = bid / NTILE;
    const int n0    = ntile * BN;

    const int l15 = lane & 15;
    const int lg  = lane >> 4;

    // R1 W staging map: thread covers d = tid&127, c-group (tid>>7)*16
    const int sd  = tid & 127;
    const int scg = (tid >> 7) * 16;
    const float* w1base = W1 + (size_t)a * C_ * C_ + n0 + sd;

    // R1 p staging map: row = tid>>2, k-offset = (tid&3)*8
    const int prow = tid >> 2;
    const int pkof = (tid & 3) * 8;

    // ---- pre-sync prologue: issue tile-0 W loads (independent of p) ----
    float wcur[16];
    #pragma unroll
    for (int i = 0; i < 4; ++i) {
        int cb = scg + i * 4;
        #pragma unroll
        for (int j = 0; j < 4; ++j)
            wcur[i * 4 + j] = w1base[(size_t)(cb + j) * C_];
    }

    // ---- Phase A: pooling (blocks 0..319), overlapped with W-load latency ----
    if (bid < NPOOLB) {
        const size_t base = (size_t)bid * (POOL_RPB * HW_);
        const float4* src = reinterpret_cast<const float4*>(x + base);  // 50176B-aligned
        for (int i = tid; i < (POOL_RPB * HW_) / 4; i += 256)
            *reinterpret_cast<float4*>(&u.pool[i * 4]) = src[i];
        __syncthreads();
        // thread t reduces row t (49 floats)
        float s = 0.f;
        #pragma unroll
        for (int j = 0; j < HW_; ++j) s += u.pool[tid * HW_ + j];
        s *= (1.0f / 49.0f);
        p[bid * POOL_RPB + tid] = f2bf(hswish(s));
        __syncthreads();   // everyone done with u.pool before head reuses LDS
    }

    cg::this_grid().sync();   // p fully visible device-wide

    // ---- Phase B: head GEMM (R1 champion structure, verbatim) ----
    f32x4 acc[8];
    #pragma unroll
    for (int n = 0; n < 8; ++n) acc[n] = (f32x4){0.f, 0.f, 0.f, 0.f};

    bf16x8 pcur = *reinterpret_cast<const bf16x8*>(p + prow * C_ + pkof);

    for (int kt = 0; kt < NK; ++kt) {
        __syncthreads();   // previous compute phase done reading LDS

        // transpose-write current tile: bf16 [d][k]
        #pragma unroll
        for (int i = 0; i < 4; ++i) {
            int cb = scg + i * 4;
            bf16x4 v;
            v[0] = f2bf(wcur[i * 4 + 0]);
            v[1] = f2bf(wcur[i * 4 + 1]);
            v[2] = f2bf(wcur[i * 4 + 2]);
            v[3] = f2bf(wcur[i * 4 + 3]);
            *reinterpret_cast<bf16x4*>(&u.head.w[sd * WLDS_STRIDE + cb]) = v;
        }
        *reinterpret_cast<bf16x8*>(&u.head.pl[prow * BK + pkof]) = pcur;

        __syncthreads();

        // issue-early prefetch of next k-tile
        float  wnxt[16];
        bf16x8 pnxt;
        if (kt + 1 < NK) {
            int k0n = (kt + 1) * BK;
            const float* wb = w1base + (size_t)k0n * C_;
            #pragma unroll
            for (int i = 0; i < 4; ++i) {
                int cb = scg + i * 4;
                #pragma unroll
                for (int j = 0; j < 4; ++j)
                    wnxt[i * 4 + j] = wb[(size_t)(cb + j) * C_];
            }
            pnxt = *reinterpret_cast<const bf16x8*>(p + prow * C_ + k0n + pkof);
        }

        // compute: wave wid owns rows [wid*16, wid*16+16)
        bf16x8 afrag = *reinterpret_cast<const bf16x8*>(&u.head.pl[(wid * 16 + l15) * BK + lg * 8]);
        #pragma unroll
        for (int n = 0; n < 8; ++n) {
            bf16x8 bfrag = *reinterpret_cast<const bf16x8*>(
                &u.head.w[(n * 16 + l15) * WLDS_STRIDE + lg * 8]);
            acc[n] = __builtin_amdgcn_mfma_f32_16x16x32_bf16(afrag, bfrag, acc[n], 0, 0, 0);
        }

        #pragma unroll
        for (int i = 0; i < 16; ++i) wcur[i] = wnxt[i];
        pcur = pnxt;
    }

    // epilogue: h_swish(acc + b1) . W2, reduce over d within block
    float partial[4] = {0.f, 0.f, 0.f, 0.f};
    #pragma unroll
    for (int n = 0; n < 8; ++n) {
        int d = n0 + n * 16 + l15;
        float b1v = b1[a * C_ + d];
        float w2v = W2[a * C_ + d];
        #pragma unroll
        for (int r = 0; r < 4; ++r) {
            float h = hswish(acc[n][r] + b1v);
            partial[r] += h * w2v;
        }
    }
    #pragma unroll
    for (int off = 8; off >= 1; off >>= 1) {
        #pragma unroll
        for (int r = 0; r < 4; ++r)
            partial[r] += __shfl_xor(partial[r], off, 64);
    }
    if (l15 == 0) {
        int brow = wid * 16 + lg * 4;   // C/D layout: row=(lane>>4)*4+r, col=lane&15
        #pragma unroll
        for (int r = 0; r < 4; ++r)
            part[ntile * (B_ * A_) + (brow + r) * A_ + a] = partial[r];
    }

    cg::this_grid().sync();   // all partials visible

    // ---- Phase C: fin (blocks 0..9) ----
    if (bid < (B_ * A_) / 256) {
        int idx = bid * 256 + tid;     // [0, 2560)
        int aa = idx % A_;
        float s = b2[aa];
        #pragma unroll
        for (int nb = 0; nb < NTILE; ++nb) s += part[nb * (B_ * A_) + idx];
        out[idx] = 1.0f / (1.0f + expf(-s));
    }
}

extern "C" void kernel_launch(void* const* d_in, const int* in_sizes, int n_in,
                              void* d_out, int out_size, void* d_ws, size_t ws_size,
                              hipStream_t stream) {
    const float* x  = (const float*)d_in[0];
    const float* W1 = (const float*)d_in[1];
    const float* b1 = (const float*)d_in[2];
    const float* W2 = (const float*)d_in[3];
    const float* b2 = (const float*)d_in[4];
    float* out = (float*)d_out;

    short* p    = (short*)d_ws;                                  // 160 KB
    float* part = (float*)((char*)d_ws + (size_t)B_ * C_ * 2);   // 100 KB

    void* args[] = { (void*)&x, (void*)&W1, (void*)&b1, (void*)&W2, (void*)&b2,
                     (void*)&p, (void*)&part, (void*)&out };
    hipLaunchCooperativeKernel((const void*)fused_kernel,
                               dim3(NBLOCKS), dim3(256), args, 0, stream);
}

// Round 7
// 81.559 us; speedup vs baseline: 2.1528x; 2.1528x over previous
//
#include <hip/hip_runtime.h>
#include <hip/hip_bf16.h>

// Problem constants
#define B_    64
#define C_    1280
#define HW_   49
#define A_    40
#define BN    32           // d-tile per block -> 1600 blocks, all co-resident
#define BK    32           // k-step (R1 champion)
#define NK    (C_/BK)      // 40
#define NTILE (C_/BN)      // 40
#define WLDS_STRIDE 40     // padded k-stride (R1's proven layout)

typedef short bf16x8 __attribute__((ext_vector_type(8)));
typedef short bf16x4 __attribute__((ext_vector_type(4)));
typedef float f32x4  __attribute__((ext_vector_type(4)));

__device__ __forceinline__ float hswish(float x) {
    float t = fminf(fmaxf(x + 3.0f, 0.0f), 6.0f);
    return x * t * (1.0f / 6.0f);
}

__device__ __forceinline__ short f2bf(float f) {
    __hip_bfloat16 h = __float2bfloat16(f);
    return __builtin_bit_cast(short, h);
}

// Kernel 1: R1 pool verbatim — avg pool (7x7) + h_swish + cvt to bf16
__global__ __launch_bounds__(256) void pool_kernel(const float* __restrict__ x,
                                                   __hip_bfloat16* __restrict__ p) {
    int t = blockIdx.x * 256 + threadIdx.x;   // [0, B_*C_), exact
    const float* src = x + (size_t)t * HW_;
    float s = 0.f;
    #pragma unroll
    for (int i = 0; i < HW_; ++i) s += src[i];
    s *= (1.0f / 49.0f);
    p[t] = __float2bfloat16(hswish(s));
}

// Kernel 2: R1 structure with BN=32. Grid = dim3(40 ntiles, 40 attrs) = 1600
// blocks, ~6.7KB LDS, low VGPR -> every block resident from t=0 (no dispatch
// tail). Each W1 row strip is exactly one aligned 128B L2 line.
__global__ __launch_bounds__(256) void head_kernel(
    const short* __restrict__ p,     // [64][1280] bf16
    const float* __restrict__ W1,    // [40][1280][1280]  ([a][k][d])
    const float* __restrict__ b1,    // [40][1280]
    const float* __restrict__ W2,    // [40][1280]
    float* __restrict__ part)        // [NTILE][64][40]
{
    __shared__ short w_lds[BN * WLDS_STRIDE];  // transposed tile [d][k], 2560 B
    __shared__ short p_lds[B_ * BK];           // [b][k], 4096 B

    const int tid  = threadIdx.x;
    const int lane = tid & 63;
    const int wid  = tid >> 6;
    const int ntile = blockIdx.x;              // 0..39
    const int a     = blockIdx.y;              // 0..39
    const int n0    = ntile * BN;

    const int l15 = lane & 15;
    const int lg  = lane >> 4;

    // W staging: thread owns d = tid&31, k-group (tid>>5)*4 (4 consecutive k)
    const int sd = tid & 31;
    const int kg = (tid >> 5) * 4;
    const float* w1base = W1 + (size_t)a * C_ * C_ + n0 + sd;

    // p staging (R1 map): row = tid>>2, k-offset = (tid&3)*8 (16B per thread)
    const int prow = tid >> 2;
    const int pkof = (tid & 3) * 8;

    f32x4 acc[2];
    acc[0] = (f32x4){0.f, 0.f, 0.f, 0.f};
    acc[1] = (f32x4){0.f, 0.f, 0.f, 0.f};

    float  wcur[4];
    bf16x8 pcur;
    // prologue: issue loads for k-tile 0
    {
        #pragma unroll
        for (int j = 0; j < 4; ++j)
            wcur[j] = w1base[(size_t)(kg + j) * C_];
        pcur = *reinterpret_cast<const bf16x8*>(p + prow * C_ + pkof);
    }

    for (int kt = 0; kt < NK; ++kt) {
        __syncthreads();   // previous compute phase done reading LDS

        // transpose-write current tile: bf16 [d][k]
        {
            bf16x4 v;
            v[0] = f2bf(wcur[0]);
            v[1] = f2bf(wcur[1]);
            v[2] = f2bf(wcur[2]);
            v[3] = f2bf(wcur[3]);
            *reinterpret_cast<bf16x4*>(&w_lds[sd * WLDS_STRIDE + kg]) = v;  // 8B write
        }
        *reinterpret_cast<bf16x8*>(&p_lds[prow * BK + pkof]) = pcur;

        __syncthreads();

        // issue-early prefetch of next k-tile (in flight across MFMA phase)
        float  wnxt[4];
        bf16x8 pnxt;
        if (kt + 1 < NK) {
            int k0n = (kt + 1) * BK;
            const float* wb = w1base + (size_t)k0n * C_;
            #pragma unroll
            for (int j = 0; j < 4; ++j)
                wnxt[j] = wb[(size_t)(kg + j) * C_];
            pnxt = *reinterpret_cast<const bf16x8*>(p + prow * C_ + k0n + pkof);
        }

        // compute: wave wid owns rows [wid*16, wid*16+16), 2 col-fragments
        bf16x8 afrag = *reinterpret_cast<const bf16x8*>(&p_lds[(wid * 16 + l15) * BK + lg * 8]);
        #pragma unroll
        for (int n = 0; n < 2; ++n) {
            bf16x8 bfrag = *reinterpret_cast<const bf16x8*>(
                &w_lds[(n * 16 + l15) * WLDS_STRIDE + lg * 8]);
            acc[n] = __builtin_amdgcn_mfma_f32_16x16x32_bf16(afrag, bfrag, acc[n], 0, 0, 0);
        }

        #pragma unroll
        for (int j = 0; j < 4; ++j) wcur[j] = wnxt[j];
        pcur = pnxt;
    }

    // epilogue: h_swish(acc + b1) . W2, reduce over this block's 32 cols
    // C/D layout: row = wid*16 + lg*4 + r, col = n0 + n*16 + l15
    float partial[4] = {0.f, 0.f, 0.f, 0.f};
    #pragma unroll
    for (int n = 0; n < 2; ++n) {
        int d = n0 + n * 16 + l15;
        float b1v = b1[a * C_ + d];
        float w2v = W2[a * C_ + d];
        #pragma unroll
        for (int r = 0; r < 4; ++r) {
            float h = hswish(acc[n][r] + b1v);
            partial[r] += h * w2v;
        }
    }
    #pragma unroll
    for (int off = 8; off >= 1; off >>= 1) {
        #pragma unroll
        for (int r = 0; r < 4; ++r)
            partial[r] += __shfl_xor(partial[r], off, 64);
    }
    if (l15 == 0) {
        int brow = wid * 16 + lg * 4;
        #pragma unroll
        for (int r = 0; r < 4; ++r)
            part[ntile * (B_ * A_) + (brow + r) * A_ + a] = partial[r];
    }
}

// Kernel 3: sum partials over the 40 d-tiles, add b2, sigmoid
__global__ __launch_bounds__(256) void fin_kernel(const float* __restrict__ part,
                                                  const float* __restrict__ b2,
                                                  float* __restrict__ out) {
    int idx = blockIdx.x * 256 + threadIdx.x;
    if (idx >= B_ * A_) return;
    int a = idx % A_;
    float s = b2[a];
    #pragma unroll
    for (int nb = 0; nb < NTILE; ++nb) s += part[nb * (B_ * A_) + idx];
    out[idx] = 1.0f / (1.0f + expf(-s));
}

extern "C" void kernel_launch(void* const* d_in, const int* in_sizes, int n_in,
                              void* d_out, int out_size, void* d_ws, size_t ws_size,
                              hipStream_t stream) {
    const float* x  = (const float*)d_in[0];
    const float* W1 = (const float*)d_in[1];
    const float* b1 = (const float*)d_in[2];
    const float* W2 = (const float*)d_in[3];
    const float* b2 = (const float*)d_in[4];
    float* out = (float*)d_out;

    __hip_bfloat16* p = (__hip_bfloat16*)d_ws;                      // 160 KB
    float* part = (float*)((char*)d_ws + (size_t)B_ * C_ * 2);      // 40*64*40*4 = 400 KB

    pool_kernel<<<(B_ * C_) / 256, 256, 0, stream>>>(x, p);
    head_kernel<<<dim3(NTILE, A_), 256, 0, stream>>>((const short*)p, W1, b1, W2, part);
    fin_kernel<<<(B_ * A_ + 255) / 256, 256, 0, stream>>>(part, b2, out);
}

// Round 8
// 60.894 us; speedup vs baseline: 2.8834x; 1.3393x over previous
//
#include <hip/hip_runtime.h>
#include <hip/hip_bf16.h>

// Problem constants
#define B_    64
#define C_    1280
#define HW_   49
#define A_    40
#define BN    128          // d-tile per block (R1 champion)
#define BK    32           // k-step (R1 champion)
#define NK    (C_/BK)      // 40 (even -> clean 2x unroll)
#define NTILE (C_/BN)      // 10
#define WLDS_STRIDE 40     // R1's padded LDS k-stride

typedef short bf16x8 __attribute__((ext_vector_type(8)));
typedef short bf16x4 __attribute__((ext_vector_type(4)));
typedef float f32x4  __attribute__((ext_vector_type(4)));

__device__ __forceinline__ float hswish(float x) {
    float t = fminf(fmaxf(x + 3.0f, 0.0f), 6.0f);
    return x * t * (1.0f / 6.0f);
}

__device__ __forceinline__ short f2bf(float f) {
    __hip_bfloat16 h = __float2bfloat16(f);
    return __builtin_bit_cast(short, h);
}

// Kernel 1: R1 pool verbatim — avg pool (7x7) + h_swish + cvt to bf16
__global__ __launch_bounds__(256) void pool_kernel(const float* __restrict__ x,
                                                   __hip_bfloat16* __restrict__ p) {
    int t = blockIdx.x * 256 + threadIdx.x;   // [0, B_*C_), exact
    const float* src = x + (size_t)t * HW_;
    float s = 0.f;
    #pragma unroll
    for (int i = 0; i < HW_; ++i) s += src[i];
    s *= (1.0f / 49.0f);
    p[t] = __float2bfloat16(hswish(s));
}

// Kernel 2: R1 head + depth-2 prefetch (named A/B buffers). The only change
// vs the 57.2us champion: two staging buffer sets so the compiler's counted
// vmcnt wait before each STORE_TILE leaves the other set's 17 loads in
// flight -> memory pipe never drains to zero inside the loop.
__global__ void head_kernel(
    const short* __restrict__ p,     // [64][1280] bf16
    const float* __restrict__ W1,    // [40][1280][1280]  ([a][k][d])
    const float* __restrict__ b1,    // [40][1280]
    const float* __restrict__ W2,    // [40][1280]
    float* __restrict__ part)        // [NTILE][64][40]
{
    __shared__ short w_lds[BN * WLDS_STRIDE];  // transposed tile: [d][k], bf16
    __shared__ short p_lds[B_ * BK];           // [b][k], bf16

    const int tid  = threadIdx.x;
    const int lane = tid & 63;
    const int wid  = tid >> 6;
    const int ntile = blockIdx.x;              // 0..9
    const int a     = blockIdx.y;              // 0..39
    const int n0    = ntile * BN;

    const int l15 = lane & 15;
    const int lg  = lane >> 4;

    // W1 staging map (R1): thread covers d = tid&127, c-group (tid>>7)*16
    const int sd  = tid & 127;
    const int scg = (tid >> 7) * 16;
    const float* w1base = W1 + (size_t)a * C_ * C_ + n0 + sd;

    // p staging map (R1): row = tid>>2, k-offset = (tid&3)*8 (16B per thread)
    const int prow = tid >> 2;
    const int pkof = (tid & 3) * 8;

    f32x4 acc[8];
    #pragma unroll
    for (int n = 0; n < 8; ++n) acc[n] = (f32x4){0.f, 0.f, 0.f, 0.f};

    float  wA[16], wB[16];
    bf16x8 pA, pB;

#define LOADW(KT, BUF) do {                                         \
        const float* _wb = w1base + (size_t)((KT) * BK) * C_;       \
        _Pragma("unroll")                                           \
        for (int _i = 0; _i < 4; ++_i) {                            \
            int _cb = scg + _i * 4;                                 \
            _Pragma("unroll")                                       \
            for (int _j = 0; _j < 4; ++_j)                          \
                BUF[_i * 4 + _j] = _wb[(size_t)(_cb + _j) * C_];    \
        }                                                           \
    } while (0)

#define LOADP(KT, BUF) do {                                         \
        BUF = *reinterpret_cast<const bf16x8*>(p + prow * C_ + (KT) * BK + pkof); \
    } while (0)

#define STORE_TILE(WBUF, PBUF) do {                                 \
        _Pragma("unroll")                                           \
        for (int _i = 0; _i < 4; ++_i) {                            \
            int _cb = scg + _i * 4;                                 \
            bf16x4 _v;                                              \
            _v[0] = f2bf(WBUF[_i * 4 + 0]);                         \
            _v[1] = f2bf(WBUF[_i * 4 + 1]);                         \
            _v[2] = f2bf(WBUF[_i * 4 + 2]);                         \
            _v[3] = f2bf(WBUF[_i * 4 + 3]);                         \
            *reinterpret_cast<bf16x4*>(&w_lds[sd * WLDS_STRIDE + _cb]) = _v; \
        }                                                           \
        *reinterpret_cast<bf16x8*>(&p_lds[prow * BK + pkof]) = PBUF; \
    } while (0)

#define COMPUTE() do {                                              \
        bf16x8 _a = *reinterpret_cast<const bf16x8*>(               \
            &p_lds[(wid * 16 + l15) * BK + lg * 8]);                \
        _Pragma("unroll")                                           \
        for (int _n = 0; _n < 8; ++_n) {                            \
            bf16x8 _b = *reinterpret_cast<const bf16x8*>(           \
                &w_lds[(_n * 16 + l15) * WLDS_STRIDE + lg * 8]);    \
            acc[_n] = __builtin_amdgcn_mfma_f32_16x16x32_bf16(_a, _b, acc[_n], 0, 0, 0); \
        }                                                           \
    } while (0)

    // prologue: two tiles in flight
    LOADW(0, wA); LOADP(0, pA);
    LOADW(1, wB); LOADP(1, pB);

    for (int kt = 0; kt < NK; kt += 2) {
        // phase A: tile kt
        __syncthreads();                 // previous compute done reading LDS
        STORE_TILE(wA, pA);              // waits only A's loads; B's 17 stay in flight
        __syncthreads();                 // tile kt visible
        if (kt + 2 < NK) { LOADW(kt + 2, wA); LOADP(kt + 2, pA); }
        COMPUTE();
        // phase B: tile kt+1
        __syncthreads();
        STORE_TILE(wB, pB);              // waits only B's loads; A's 17 stay in flight
        __syncthreads();
        if (kt + 3 < NK) { LOADW(kt + 3, wB); LOADP(kt + 3, pB); }
        COMPUTE();
    }
#undef LOADW
#undef LOADP
#undef STORE_TILE
#undef COMPUTE

    // epilogue (R1 verbatim): h_swish(acc + b1) . W2, reduce over d
    float partial[4] = {0.f, 0.f, 0.f, 0.f};
    #pragma unroll
    for (int n = 0; n < 8; ++n) {
        int d = n0 + n * 16 + l15;
        float b1v = b1[a * C_ + d];
        float w2v = W2[a * C_ + d];
        #pragma unroll
        for (int r = 0; r < 4; ++r) {
            float h = hswish(acc[n][r] + b1v);
            partial[r] += h * w2v;
        }
    }
    #pragma unroll
    for (int off = 8; off >= 1; off >>= 1) {
        #pragma unroll
        for (int r = 0; r < 4; ++r)
            partial[r] += __shfl_xor(partial[r], off, 64);
    }
    if (l15 == 0) {
        int brow = wid * 16 + lg * 4;   // C/D layout: row=(lane>>4)*4+r, col=lane&15
        #pragma unroll
        for (int r = 0; r < 4; ++r)
            part[ntile * (B_ * A_) + (brow + r) * A_ + a] = partial[r];
    }
}

// Kernel 3: sum partials over the 10 d-tiles, add b2, sigmoid
__global__ __launch_bounds__(256) void fin_kernel(const float* __restrict__ part,
                                                  const float* __restrict__ b2,
                                                  float* __restrict__ out) {
    int idx = blockIdx.x * 256 + threadIdx.x;
    if (idx >= B_ * A_) return;
    int a = idx % A_;
    float s = b2[a];
    #pragma unroll
    for (int nb = 0; nb < NTILE; ++nb) s += part[nb * (B_ * A_) + idx];
    out[idx] = 1.0f / (1.0f + expf(-s));
}

extern "C" void kernel_launch(void* const* d_in, const int* in_sizes, int n_in,
                              void* d_out, int out_size, void* d_ws, size_t ws_size,
                              hipStream_t stream) {
    const float* x  = (const float*)d_in[0];
    const float* W1 = (const float*)d_in[1];
    const float* b1 = (const float*)d_in[2];
    const float* W2 = (const float*)d_in[3];
    const float* b2 = (const float*)d_in[4];
    float* out = (float*)d_out;

    __hip_bfloat16* p = (__hip_bfloat16*)d_ws;                      // 160 KB
    float* part = (float*)((char*)d_ws + (size_t)B_ * C_ * 2);      // 100 KB

    pool_kernel<<<(B_ * C_) / 256, 256, 0, stream>>>(x, p);
    head_kernel<<<dim3(NTILE, A_), 256, 0, stream>>>((const short*)p, W1, b1, W2, part);
    fin_kernel<<<(B_ * A_ + 255) / 256, 256, 0, stream>>>(part, b2, out);
}